// Round 2
// baseline (1373.956 us; speedup 1.0000x reference)
//
#include <hip/hip_runtime.h>
#include <stdint.h>

// Poisson spike encoding, bit-exact vs JAX CPU reference.
// counts[i,j] ~ Knuth-Poisson(img[i]) using threefry2x32 partitionable RNG,
// spikes = cummax_j(counts+j) > j, output [T, N] as int32 0/1.

#define TWIN 500
#define MAX_DRAWS 28   // P(any of 1.3e8 elements needs >28 draws) ~ 1e-22

struct Subkeys {
  uint32_t a[MAX_DRAWS];
  uint32_t b[MAX_DRAWS];
};

__host__ __device__ __forceinline__ void tf2x32(uint32_t k0, uint32_t k1,
                                                uint32_t x0, uint32_t x1,
                                                uint32_t& o0, uint32_t& o1) {
  const uint32_t ks2 = k0 ^ k1 ^ 0x1BD11BDAu;
  x0 += k0; x1 += k1;
#define TF_RND(r) { x0 += x1; x1 = (x1 << (r)) | (x1 >> (32 - (r))); x1 ^= x0; }
  TF_RND(13) TF_RND(15) TF_RND(26) TF_RND(6)
  x0 += k1;  x1 += ks2 + 1u;
  TF_RND(17) TF_RND(29) TF_RND(16) TF_RND(24)
  x0 += ks2; x1 += k0 + 2u;
  TF_RND(13) TF_RND(15) TF_RND(26) TF_RND(6)
  x0 += k0;  x1 += k1 + 3u;
  TF_RND(17) TF_RND(29) TF_RND(16) TF_RND(24)
  x0 += k1;  x1 += ks2 + 4u;
  TF_RND(13) TF_RND(15) TF_RND(26) TF_RND(6)
  x0 += ks2; x1 += k0 + 5u;
#undef TF_RND
  o0 = x0; o1 = x1;
}

// Cephes/Eigen plog<float>, as emitted by XLA:CPU's vectorized log rewrite.
// Variant V1: Horner chain + tail e*q1 all FMA-contracted (AVX2 vfmadd codegen).
__device__ __forceinline__ float cephes_logf(float u) {
  float x = fmaxf(u, __uint_as_float(0x00800000u));      // clamp denorm/zero
  int emm0 = (int)(__float_as_uint(x) >> 23);
  x = __uint_as_float((__float_as_uint(x) & 0x807FFFFFu) | 0x3F000000u); // [0.5,1)
  float e = (float)(emm0 - 127) + 1.0f;
  const bool mask = x < 0.707106781186547524f;           // cephes_SQRTHF
  float tmp = mask ? x : 0.0f;
  x = x - 1.0f;
  e = e - (mask ? 1.0f : 0.0f);
  x = x + tmp;
  float z = x * x;
  float y = 7.0376836292E-2f;
  y = fmaf(y, x, -1.1514610310E-1f);
  y = fmaf(y, x,  1.1676998740E-1f);
  y = fmaf(y, x, -1.2420140846E-1f);
  y = fmaf(y, x,  1.4249322787E-1f);
  y = fmaf(y, x, -1.6668057665E-1f);
  y = fmaf(y, x,  2.0000714765E-1f);
  y = fmaf(y, x, -2.4999993993E-1f);
  y = fmaf(y, x,  3.3333331174E-1f);
  y = y * x;
  y = y * z;
  y = fmaf(e, -2.12194440e-4f, y);   // y += e*q1  (V1: fused)
  y = fmaf(z, -0.5f, y);             // y -= 0.5*z (product exact; fusion-neutral)
  x = x + y;
  x = fmaf(e, 0.693359375f, x);      // x += e*q2  (product exact; fusion-neutral)
  return x;
}

__global__ __launch_bounds__(256) void CustomPoisson_12292196401945_kernel(
    const float* __restrict__ img, int* __restrict__ out,
    Subkeys sk, int N) {
  const int i = blockIdx.x * blockDim.x + threadIdx.x;
  if (i >= N) return;
  const float neg_lam = -img[i];
  uint32_t e = (uint32_t)i * TWIN;   // flat row-major index into [N, TWIN]
  int runmax = 0;                    // running max of (count_j + j)

  for (int j = 0; j < TWIN; ++j, ++e) {
    // Knuth: count = max{ n>=0 : S_n > -lam }, S_n = sum of cephes_log(u_i)
    float S = 0.0f;
    int k = 0;
    #pragma unroll 1
    for (int d = 0; d < MAX_DRAWS; ++d) {
      uint32_t b1, b2;
      tf2x32(sk.a[d], sk.b[d], 0u, e, b1, b2);
      const uint32_t bits = b1 ^ b2;                       // partitionable join
      const float u = __uint_as_float((bits >> 9) | 0x3F800000u) - 1.0f;
      S += cephes_logf(u);
      if (S > neg_lam) k++; else break;
    }
    const int ends = k + j;
    runmax = runmax > ends ? runmax : ends;
    out[(size_t)j * (size_t)N + (size_t)i] = (runmax > j) ? 1 : 0;
  }
}

extern "C" void kernel_launch(void* const* d_in, const int* in_sizes, int n_in,
                              void* d_out, int out_size, void* d_ws, size_t ws_size,
                              hipStream_t stream) {
  const float* img = (const float*)d_in[0];
  int* out = (int*)d_out;
  const int N = in_sizes[0];  // 262144

  // Host-side subkey chain: rng = (0, 42) = threefry_seed(42).
  // Partitionable (fold-like) split: new_rng = tf(rng;(0,0)), subkey = tf(rng;(0,1)).
  Subkeys sk;
  uint32_t r0 = 0u, r1 = 42u;
  for (int d = 0; d < MAX_DRAWS; ++d) {
    uint32_t s0, s1, n0, n1;
    tf2x32(r0, r1, 0u, 1u, s0, s1);  // subkey for draw d (iteration d+1)
    tf2x32(r0, r1, 0u, 0u, n0, n1);  // next rng
    sk.a[d] = s0; sk.b[d] = s1;
    r0 = n0; r1 = n1;
  }

  dim3 block(256);
  dim3 grid((N + 255) / 256);
  hipLaunchKernelGGL(CustomPoisson_12292196401945_kernel, grid, block, 0, stream,
                     img, out, sk, N);
}

// Round 3
// 943.163 us; speedup vs baseline: 1.4568x; 1.4568x over previous
//
#include <hip/hip_runtime.h>
#include <stdint.h>

// Poisson spike encoding, bit-exact vs JAX CPU reference.
// Stream-restructured: each wave iteration = exactly one Knuth draw per live
// lane; elements advance per-lane, spike bits buffered 50/chunk, coalesced flush.

#define TWIN 500
#define CHUNK 50          // 10 uniform chunks of 50 time-steps
#define MAX_DRAWS 28      // matches verified round-2 cap (P(reach) ~ 1e-22)

struct Subkeys {
  uint32_t a[MAX_DRAWS];
  uint32_t b[MAX_DRAWS];
};

__host__ __device__ __forceinline__ uint32_t rotl32(uint32_t x, uint32_t r) {
#if defined(__HIP_DEVICE_COMPILE__) && __has_builtin(__builtin_amdgcn_alignbit)
  return __builtin_amdgcn_alignbit(x, x, 32u - r);   // 1 VALU op guaranteed
#else
  return (x << r) | (x >> (32u - r));
#endif
}

__host__ __device__ __forceinline__ void tf2x32(uint32_t k0, uint32_t k1,
                                                uint32_t x0, uint32_t x1,
                                                uint32_t& o0, uint32_t& o1) {
  const uint32_t ks2 = k0 ^ k1 ^ 0x1BD11BDAu;
  x0 += k0; x1 += k1;
#define TF_RND(r) { x0 += x1; x1 = rotl32(x1, (r)); x1 ^= x0; }
  TF_RND(13) TF_RND(15) TF_RND(26) TF_RND(6)
  x0 += k1;  x1 += ks2 + 1u;
  TF_RND(17) TF_RND(29) TF_RND(16) TF_RND(24)
  x0 += ks2; x1 += k0 + 2u;
  TF_RND(13) TF_RND(15) TF_RND(26) TF_RND(6)
  x0 += k0;  x1 += k1 + 3u;
  TF_RND(17) TF_RND(29) TF_RND(16) TF_RND(24)
  x0 += k1;  x1 += ks2 + 4u;
  TF_RND(13) TF_RND(15) TF_RND(26) TF_RND(6)
  x0 += ks2; x1 += k0 + 5u;
#undef TF_RND
  o0 = x0; o1 = x1;
}

// Cephes/Eigen plog<float>, FMA-contracted exactly as verified in round 2.
__device__ __forceinline__ float cephes_logf(float u) {
  float x = fmaxf(u, __uint_as_float(0x00800000u));
  int emm0 = (int)(__float_as_uint(x) >> 23);
  x = __uint_as_float((__float_as_uint(x) & 0x807FFFFFu) | 0x3F000000u);
  float e = (float)(emm0 - 127) + 1.0f;
  const bool mask = x < 0.707106781186547524f;
  float tmp = mask ? x : 0.0f;
  x = x - 1.0f;
  e = e - (mask ? 1.0f : 0.0f);
  x = x + tmp;
  float z = x * x;
  float y = 7.0376836292E-2f;
  y = fmaf(y, x, -1.1514610310E-1f);
  y = fmaf(y, x,  1.1676998740E-1f);
  y = fmaf(y, x, -1.2420140846E-1f);
  y = fmaf(y, x,  1.4249322787E-1f);
  y = fmaf(y, x, -1.6668057665E-1f);
  y = fmaf(y, x,  2.0000714765E-1f);
  y = fmaf(y, x, -2.4999993993E-1f);
  y = fmaf(y, x,  3.3333331174E-1f);
  y = y * x;
  y = y * z;
  y = fmaf(e, -2.12194440e-4f, y);
  y = fmaf(z, -0.5f, y);
  x = x + y;
  x = fmaf(e, 0.693359375f, x);
  return x;
}

__global__ __launch_bounds__(256) void CustomPoisson_12292196401945_kernel(
    const float* __restrict__ img, int* __restrict__ out,
    Subkeys sk, int N) {
  __shared__ uint2 lk[MAX_DRAWS];
  if (threadIdx.x < MAX_DRAWS) {
    lk[threadIdx.x] = make_uint2(sk.a[threadIdx.x], sk.b[threadIdx.x]);
  }
  __syncthreads();

  const int i = blockIdx.x * blockDim.x + threadIdx.x;
  if (i >= N) return;
  const float neg_lam = -img[i];
  const uint32_t k0a = sk.a[0], k0b = sk.b[0];  // uniform -> SGPRs

  uint32_t e = (uint32_t)i * TWIN;  // flat [N,T] element counter for threefry
  int runmax = 0;                   // running cummax of (count_j + j)
  float S = 0.0f;                   // per-element running sum of log(u)
  int k = 0;                        // per-element survived-draw count
  int d = 0;                        // per-element draw index
  uint32_t cka = k0a, ckb = k0b;    // current subkey

  for (int base = 0; base < TWIN; base += CHUNK) {
    uint64_t bits = 0;
    int jj = 0;
    int j = base;
    bool done = false;

    while (__any(!done)) {
      if (!done) {
        // prefetch next subkey (consumed next iteration if element survives)
        int dn = d + 1; dn = dn > MAX_DRAWS - 1 ? MAX_DRAWS - 1 : dn;
        const uint2 nk = lk[dn];

        uint32_t b1, b2;
        tf2x32(cka, ckb, 0u, e, b1, b2);
        const uint32_t rb = b1 ^ b2;
        const float u = __uint_as_float((rb >> 9) | 0x3F800000u) - 1.0f;
        S += cephes_logf(u);

        const bool alive = S > neg_lam;
        const int k2 = k + (alive ? 1 : 0);
        const bool fin = (!alive) || (d == MAX_DRAWS - 1);

        const int ends = k2 + j;
        const int rm2 = runmax > ends ? runmax : ends;
        runmax = fin ? rm2 : runmax;
        bits |= (uint64_t)((fin && (runmax > j)) ? 1u : 0u) << jj;

        // advance element state (branchless)
        S   = fin ? 0.0f : S;
        k   = fin ? 0 : k2;
        d   = fin ? 0 : d + 1;
        cka = fin ? k0a : nk.x;
        ckb = fin ? k0b : nk.y;
        e  += fin ? 1u : 0u;
        j  += fin ? 1 : 0;
        jj += fin ? 1 : 0;
        done = (jj == CHUNK);
      }
    }

    // coalesced flush: lane i writes column i of rows [base, base+CHUNK)
    size_t op = (size_t)base * (size_t)N + (size_t)i;
    #pragma unroll
    for (int t = 0; t < CHUNK; ++t) {
      out[op] = (int)((uint32_t)(bits >> t) & 1u);
      op += (size_t)N;
    }
  }
}

extern "C" void kernel_launch(void* const* d_in, const int* in_sizes, int n_in,
                              void* d_out, int out_size, void* d_ws, size_t ws_size,
                              hipStream_t stream) {
  const float* img = (const float*)d_in[0];
  int* out = (int*)d_out;
  const int N = in_sizes[0];  // 262144

  // Host-side subkey chain: rng = (0, 42); partitionable fold-like split.
  Subkeys sk;
  uint32_t r0 = 0u, r1 = 42u;
  for (int d = 0; d < MAX_DRAWS; ++d) {
    uint32_t s0, s1, n0, n1;
    tf2x32(r0, r1, 0u, 1u, s0, s1);  // subkey for draw d
    tf2x32(r0, r1, 0u, 0u, n0, n1);  // next rng
    sk.a[d] = s0; sk.b[d] = s1;
    r0 = n0; r1 = n1;
  }

  dim3 block(256);
  dim3 grid((N + 255) / 256);
  hipLaunchKernelGGL(CustomPoisson_12292196401945_kernel, grid, block, 0, stream,
                     img, out, sk, N);
}

// Round 4
// 907.945 us; speedup vs baseline: 1.5133x; 1.0388x over previous
//
#include <hip/hip_runtime.h>
#include <stdint.h>

// Poisson spike encoding, bit-exact vs JAX CPU reference (verified round 2/3).
// Round 4: 2 threads/pixel (250 steps + 26 warmup), 8 waves/SIMD occupancy,
// slimmed streaming inner loop (idempotent runmax/bit updates, no cap-check).

#define TWIN 500
#define HALF 250
#define WARM 26          // cummax carry distance; P(count>=26) ~ 1e-18 dataset-wide
#define CHUNK 25         // spike bits buffered per flush (uint32)
#define NKEYS 32         // padded subkey table (draws beyond ~15 unreachable)
#define DCAP 30          // hard safety cap, unreachable on this input

struct Subkeys {
  uint32_t a[NKEYS];
  uint32_t b[NKEYS];
};

__host__ __device__ __forceinline__ uint32_t rotl32(uint32_t x, uint32_t r) {
#if defined(__HIP_DEVICE_COMPILE__) && __has_builtin(__builtin_amdgcn_alignbit)
  return __builtin_amdgcn_alignbit(x, x, 32u - r);   // 1 VALU op
#else
  return (x << r) | (x >> (32u - r));
#endif
}

__host__ __device__ __forceinline__ void tf2x32(uint32_t k0, uint32_t k1,
                                                uint32_t x0, uint32_t x1,
                                                uint32_t& o0, uint32_t& o1) {
  const uint32_t ks2 = k0 ^ k1 ^ 0x1BD11BDAu;
  x0 += k0; x1 += k1;
#define TF_RND(r) { x0 += x1; x1 = rotl32(x1, (r)); x1 ^= x0; }
  TF_RND(13) TF_RND(15) TF_RND(26) TF_RND(6)
  x0 += k1;  x1 += ks2 + 1u;
  TF_RND(17) TF_RND(29) TF_RND(16) TF_RND(24)
  x0 += ks2; x1 += k0 + 2u;
  TF_RND(13) TF_RND(15) TF_RND(26) TF_RND(6)
  x0 += k0;  x1 += k1 + 3u;
  TF_RND(17) TF_RND(29) TF_RND(16) TF_RND(24)
  x0 += k1;  x1 += ks2 + 4u;
  TF_RND(13) TF_RND(15) TF_RND(26) TF_RND(6)
  x0 += ks2; x1 += k0 + 5u;
#undef TF_RND
  o0 = x0; o1 = x1;
}

// Cephes/Eigen plog<float>, FMA-contracted exactly as bit-verified in round 2.
__device__ __forceinline__ float cephes_logf(float u) {
  float x = fmaxf(u, __uint_as_float(0x00800000u));
  int emm0 = (int)(__float_as_uint(x) >> 23);
  x = __uint_as_float((__float_as_uint(x) & 0x807FFFFFu) | 0x3F000000u);
  float e = (float)(emm0 - 127) + 1.0f;
  const bool mask = x < 0.707106781186547524f;
  float tmp = mask ? x : 0.0f;
  x = x - 1.0f;
  e = e - (mask ? 1.0f : 0.0f);
  x = x + tmp;
  float z = x * x;
  float y = 7.0376836292E-2f;
  y = fmaf(y, x, -1.1514610310E-1f);
  y = fmaf(y, x,  1.1676998740E-1f);
  y = fmaf(y, x, -1.2420140846E-1f);
  y = fmaf(y, x,  1.4249322787E-1f);
  y = fmaf(y, x, -1.6668057665E-1f);
  y = fmaf(y, x,  2.0000714765E-1f);
  y = fmaf(y, x, -2.4999993993E-1f);
  y = fmaf(y, x,  3.3333331174E-1f);
  y = y * x;
  y = y * z;
  y = fmaf(e, -2.12194440e-4f, y);
  y = fmaf(z, -0.5f, y);
  x = x + y;
  x = fmaf(e, 0.693359375f, x);
  return x;
}

// One Knuth draw for the lane's current element (j); advances element on fin.
// RECORD_BITS: also OR the (idempotent) spike bit for position j-base.
#define DRAW_BODY(RECORD_BITS)                                              \
  {                                                                         \
    const uint32_t dn = (uint32_t)(d + 1) & (NKEYS - 1);                    \
    const uint2 nk = lk[dn];                                                \
    uint32_t x0 = cka;                                                      \
    uint32_t x1 = e_row + (uint32_t)j + ckb;                                \
    const uint32_t ks2 = cka ^ ckb ^ 0x1BD11BDAu;                           \
    { uint32_t t0 = x0, t1 = x1;                                            \
      /* 20 threefry rounds + injections, keys (cka,ckb,ks2) */             \
      t0 += t1; t1 = rotl32(t1, 13); t1 ^= t0;                              \
      t0 += t1; t1 = rotl32(t1, 15); t1 ^= t0;                              \
      t0 += t1; t1 = rotl32(t1, 26); t1 ^= t0;                              \
      t0 += t1; t1 = rotl32(t1,  6); t1 ^= t0;                              \
      t0 += ckb; t1 += ks2 + 1u;                                            \
      t0 += t1; t1 = rotl32(t1, 17); t1 ^= t0;                              \
      t0 += t1; t1 = rotl32(t1, 29); t1 ^= t0;                              \
      t0 += t1; t1 = rotl32(t1, 16); t1 ^= t0;                              \
      t0 += t1; t1 = rotl32(t1, 24); t1 ^= t0;                              \
      t0 += ks2; t1 += cka + 2u;                                            \
      t0 += t1; t1 = rotl32(t1, 13); t1 ^= t0;                              \
      t0 += t1; t1 = rotl32(t1, 15); t1 ^= t0;                              \
      t0 += t1; t1 = rotl32(t1, 26); t1 ^= t0;                              \
      t0 += t1; t1 = rotl32(t1,  6); t1 ^= t0;                              \
      t0 += cka; t1 += ckb + 3u;                                            \
      t0 += t1; t1 = rotl32(t1, 17); t1 ^= t0;                              \
      t0 += t1; t1 = rotl32(t1, 29); t1 ^= t0;                              \
      t0 += t1; t1 = rotl32(t1, 16); t1 ^= t0;                              \
      t0 += t1; t1 = rotl32(t1, 24); t1 ^= t0;                              \
      t0 += ckb; t1 += ks2 + 4u;                                            \
      t0 += t1; t1 = rotl32(t1, 13); t1 ^= t0;                              \
      t0 += t1; t1 = rotl32(t1, 15); t1 ^= t0;                              \
      t0 += t1; t1 = rotl32(t1, 26); t1 ^= t0;                              \
      t0 += t1; t1 = rotl32(t1,  6); t1 ^= t0;                              \
      t0 += ks2; t1 += cka + 5u;                                            \
      x0 = t0; x1 = t1; }                                                   \
    const uint32_t rb = x0 ^ x1;                                            \
    const float u = __uint_as_float((rb >> 9) | 0x3F800000u) - 1.0f;        \
    S += cephes_logf(u);                                                    \
    const bool alive = S > neg_lam;                                         \
    const int k2 = k + (alive ? 1 : 0);                                     \
    const bool fin = (!alive) || (d >= DCAP);                               \
    const int ends = k2 + j;                                                \
    runmax = runmax > ends ? runmax : ends;  /* idempotent */               \
    RECORD_BITS                                                             \
    S   = fin ? 0.0f : S;                                                   \
    k   = fin ? 0 : k2;                                                     \
    d   = fin ? 0 : d + 1;                                                  \
    cka = fin ? k0a : nk.x;                                                 \
    ckb = fin ? k0b : nk.y;                                                 \
    j  += fin ? 1 : 0;                                                      \
  }

__global__ __launch_bounds__(256, 8) void CustomPoisson_12292196401945_kernel(
    const float* __restrict__ img, int* __restrict__ out,
    Subkeys sk, int N) {
  __shared__ uint2 lk[NKEYS];
  if (threadIdx.x < NKEYS) {
    lk[threadIdx.x] = make_uint2(sk.a[threadIdx.x], sk.b[threadIdx.x]);
  }
  __syncthreads();

  const int tid = blockIdx.x * blockDim.x + threadIdx.x;
  const int i = (tid >= N) ? (tid - N) : tid;       // pixel
  const int h = (tid >= N) ? 1 : 0;                 // row half (wave-uniform)
  const float neg_lam = -img[i];
  const uint32_t k0a = sk.a[0], k0b = sk.b[0];      // uniform -> SGPRs
  const uint32_t e_row = (uint32_t)i * TWIN;

  const int jstart = h ? HALF : 0;
  const int jend = jstart + HALF;

  int j = h ? (jstart - WARM) : 0;  // warmup start (h=1 only)
  float S = 0.0f;
  int k = 0, d = 0;
  uint32_t cka = k0a, ckb = k0b;
  int runmax = 0;

  // Warmup: rebuild cummax carry across the half boundary (no bit recording).
  while (__any(j < jstart)) {
    if (j < jstart) DRAW_BODY()
  }

  uint32_t off = (uint32_t)jstart * (uint32_t)N + (uint32_t)i;  // fits 32b
  for (int base = jstart; base < jend; base += CHUNK) {
    uint32_t bits = 0;
    const int lim = base + CHUNK;
    while (__any(j < lim)) {
      if (j < lim) DRAW_BODY(
        bits |= (uint32_t)((runmax > j) ? 1 : 0) << (uint32_t)(j - base);
      )
    }
    // coalesced flush: lane writes its column for rows [base, base+CHUNK)
    #pragma unroll
    for (int t = 0; t < CHUNK; ++t) {
      out[off] = (int)((bits >> t) & 1u);
      off += (uint32_t)N;
    }
  }
}

extern "C" void kernel_launch(void* const* d_in, const int* in_sizes, int n_in,
                              void* d_out, int out_size, void* d_ws, size_t ws_size,
                              hipStream_t stream) {
  const float* img = (const float*)d_in[0];
  int* out = (int*)d_out;
  const int N = in_sizes[0];  // 262144

  // Host-side subkey chain: rng = (0, 42); partitionable fold-like split.
  Subkeys sk;
  uint32_t r0 = 0u, r1 = 42u;
  for (int d = 0; d < NKEYS; ++d) {
    uint32_t s0, s1, n0, n1;
    tf2x32(r0, r1, 0u, 1u, s0, s1);  // subkey for draw d
    tf2x32(r0, r1, 0u, 0u, n0, n1);  // next rng
    sk.a[d] = s0; sk.b[d] = s1;
    r0 = n0; r1 = n1;
  }

  dim3 block(256);
  dim3 grid((2 * N + 255) / 256);
  hipLaunchKernelGGL(CustomPoisson_12292196401945_kernel, grid, block, 0, stream,
                     img, out, sk, N);
}